// Round 2
// baseline (1265.793 us; speedup 1.0000x reference)
//
#include <hip/hip_runtime.h>
#include <hip/hip_bf16.h>

#define BB 32
#define NN 2048
#define DD 512
#define DGG 1024
#define CC 32          // scan chunks per sequence
#define LLEN 64        // scan chunk length (CC*LLEN == NN)

typedef short bf16x8 __attribute__((ext_vector_type(8)));
typedef float f32x4  __attribute__((ext_vector_type(4)));

__device__ __forceinline__ unsigned short f2bf(float f){
    __hip_bfloat16 h = __float2bfloat16(f);
    return *reinterpret_cast<unsigned short*>(&h);
}
__device__ __forceinline__ float bf2f(unsigned short u){
    unsigned int x = ((unsigned int)u) << 16;
    return __uint_as_float(x);
}
__device__ __forceinline__ float sigm(float x){ return 1.0f/(1.0f + __expf(-x)); }

// async global->LDS, 16B per lane; LDS dest = wave-uniform base + lane*16 (m97/m104)
__device__ __forceinline__ void gl_lds16(const unsigned short* g, unsigned short* l){
    __builtin_amdgcn_global_load_lds(
        (const __attribute__((address_space(1))) unsigned int*)g,
        (__attribute__((address_space(3))) unsigned int*)l, 16, 0, 0);
}

// ---------------------------------------------------------------------------
// Weight prep: transpose + cast  in[K][N] fp32  ->  out[N][K] bf16.
// ---------------------------------------------------------------------------
__global__ __launch_bounds__(256)
void wt_prep(const float* __restrict__ in, unsigned short* __restrict__ out,
             int K, int N)
{
    __shared__ float t[32][33];
    const int tid = threadIdx.x;
    const int r = tid >> 3;            // 0..31
    const int c = (tid & 7) << 2;      // 0,4,..,28
    const int n0 = blockIdx.x * 32;
    const int k0 = blockIdx.y * 32;
    float4 v = *(const float4*)(in + (size_t)(k0 + r) * N + n0 + c);
    t[r][c] = v.x; t[r][c+1] = v.y; t[r][c+2] = v.z; t[r][c+3] = v.w;
    __syncthreads();
    ushort4 o;
    o.x = f2bf(t[c+0][r]); o.y = f2bf(t[c+1][r]);
    o.z = f2bf(t[c+2][r]); o.w = f2bf(t[c+3][r]);
    *(ushort4*)(out + (size_t)(n0 + r) * K + k0 + c) = o;
}

// ---------------------------------------------------------------------------
// Paired weight prep with 16-column interleave:
//   out[2N][K] bf16, out row n holds column ((n>>5)*16 + (n&15)) of matrix
//   h = (n>>4)&1  (h=0 -> in0, h=1 -> in1), transposed.
// Epilogue pairing: GEMM n-cols (base+ni*16+lm, ni even/odd) give mat0/mat1
// at the SAME source column c = base/2 + (ni>>1)*16 + lm.
// ---------------------------------------------------------------------------
__global__ __launch_bounds__(256)
void wt_prep_pair(const float* __restrict__ in0, const float* __restrict__ in1,
                  unsigned short* __restrict__ out, int K, int N)
{
    __shared__ float t[32][33];
    const int tid = threadIdx.x;
    const int bx  = blockIdx.x;            // group of 32 output rows
    const int k0  = blockIdx.y * 32;
    const int kk  = tid >> 3;              // 0..31
    const int rq  = (tid & 7) << 2;        // 0,4,..,28 (stays within one 16-half)
    const float* src = ((rq >> 4) & 1) ? in1 : in0;
    const int c0 = bx * 16 + (rq & 15);
    float4 v = *(const float4*)(src + (size_t)(k0 + kk) * N + c0);
    t[kk][rq] = v.x; t[kk][rq+1] = v.y; t[kk][rq+2] = v.z; t[kk][rq+3] = v.w;
    __syncthreads();
    const int rr = tid >> 3;               // output row within group
    const int kc = (tid & 7) << 2;
    ushort4 o;
    o.x = f2bf(t[kc+0][rr]); o.y = f2bf(t[kc+1][rr]);
    o.z = f2bf(t[kc+2][rr]); o.w = f2bf(t[kc+3][rr]);
    *(ushort4*)(out + (size_t)(bx * 32 + rr) * K + k0 + kc) = o;
}

// fp32 -> bf16 cast, 4 elems/thread
__global__ __launch_bounds__(256)
void cast_bf16(const float* __restrict__ in, unsigned short* __restrict__ out)
{
    size_t i = ((size_t)blockIdx.x * 256 + threadIdx.x) * 4;
    float4 v = *(const float4*)(in + i);
    ushort4 o;
    o.x = f2bf(v.x); o.y = f2bf(v.y); o.z = f2bf(v.z); o.w = f2bf(v.w);
    *(ushort4*)(out + i) = o;
}

// ---------------------------------------------------------------------------
// gemm256: 256x256 tile, BK=32, ring-4 LDS pipeline (3 tiles in flight,
// counted vmcnt -- slots are SEPARATE __shared__ objects + full unroll so the
// compiler's waitcnt pass can prove non-aliasing and keep loads in flight).
// 512 thr = 8 waves (2Mx4N), wave tile 128x64, acc[8][4] 16x16x32 MFMA.
// A[M][K] bf16, Bt[NI][K] bf16 (pre-transposed; NI = B-panel rows).
//   MODE 0: out0 = A@B + bias0
//   MODE 2: out0 = sigmoid(A@B + bias0)
//   MODE 5: paired B (Wi|Wf interleaved): si=silu(p0+b0); fv=sigm(p1+b1);
//           lam=lb+(1-lb)*fv -> out0 ; u=(1-lam)*si -> out1   (NOUT=NI/2)
//   MODE 6: paired B (W1|W2): out0 = silu(p0+b0)*(p1+b1)      (NOUT=NI/2)
// ---------------------------------------------------------------------------
template<int MODE, int K, int NI>
__global__ __launch_bounds__(512, 2)
void gemm256(const unsigned short* __restrict__ A,
             const unsigned short* __restrict__ Bt,
             const float* __restrict__ bias0,
             const float* __restrict__ bias1,
             unsigned short* __restrict__ out0,
             unsigned short* __restrict__ out1,
             const int* __restrict__ lbp, int Mtiles)
{
    constexpr int NT   = K / 32;                        // K-tiles
    constexpr int Ntl  = NI / 256;                      // n-tiles
    constexpr int NOUT = (MODE >= 5) ? NI / 2 : NI;     // output row width
    constexpr int TILE = 256 * 32;                      // 16 KiB per slot
    // ring-4 slots as DISTINCT shared objects (alias-analysis-friendly)
    __shared__ unsigned short As0[TILE], As1[TILE], As2[TILE], As3[TILE];
    __shared__ unsigned short Bs0[TILE], Bs1[TILE], Bs2[TILE], Bs3[TILE];
#define ASL(i) ((i)==0?As0:(i)==1?As1:(i)==2?As2:As3)
#define BSL(i) ((i)==0?Bs0:(i)==1?Bs1:(i)==2?Bs2:Bs3)

    const int tid  = threadIdx.x;
    const int wave = tid >> 6;
    const int lane = tid & 63;
    const int lm   = lane & 15;
    const int quad = lane >> 4;
    const int wr   = (wave >> 2) * 128;
    const int wc   = (wave & 3) * 64;

    // XCD-aware bijective swizzle (nwg % 8 == 0 for all shapes here), n-fast.
    const int nwg = Mtiles * Ntl;
    const int h   = blockIdx.x;
    const int wg  = (h & 7) * (nwg >> 3) + (h >> 3);
    const int bm  = wg / Ntl;
    const int bn  = wg - bm * Ntl;
    const size_t m0 = (size_t)bm * 256;
    const int    n0 = bn * 256;

    // staging: linear LDS dest, XOR-pre-swizzled global source (rule #21)
    const int lrow  = lane >> 2;
    const int oslot = ((lane & 3) ^ ((lane >> 3) & 3)) << 3;
    const unsigned short* gA = A  + (m0 + (size_t)(wave * 16 + lrow)) * K + oslot;
    const unsigned short* gB = Bt + ((size_t)n0 + wave * 16 + lrow) * K + oslot;
    const int lbase = (wave * 16) * 32;                 // wave-uniform LDS base
    const int aslot = (quad ^ ((lm >> 1) & 3)) << 3;    // swizzled read slot

#define STAGE(kt, i) do {                                               \
        const unsigned short* ga_ = gA + (kt) * 32;                     \
        const unsigned short* gb_ = gB + (kt) * 32;                     \
        gl_lds16(ga_,                  ASL(i) + lbase);                 \
        gl_lds16(ga_ + (size_t)128*K,  ASL(i) + lbase + 128*32);        \
        gl_lds16(gb_,                  BSL(i) + lbase);                 \
        gl_lds16(gb_ + (size_t)128*K,  BSL(i) + lbase + 128*32);        \
    } while (0)

    f32x4 acc[8][4];
    const f32x4 zero = {0.f, 0.f, 0.f, 0.f};
    #pragma unroll
    for (int i = 0; i < 8; ++i)
        #pragma unroll
        for (int j = 0; j < 4; ++j) acc[i][j] = zero;

    // prologue: tiles 0,1,2 in flight; wait tile 0 only (8 newest stay out)
    STAGE(0, 0);
    STAGE(1, 1);
    STAGE(2, 2);
    asm volatile("s_waitcnt vmcnt(8)" ::: "memory");
    __builtin_amdgcn_s_barrier();

    #pragma unroll
    for (int t = 0; t < NT; ++t) {
        if (t + 3 < NT) STAGE(t + 3, (t + 3) & 3);   // slot of tile t-1 (freed)

        const unsigned short* Ab = ASL(t & 3);
        const unsigned short* Bb = BSL(t & 3);
        bf16x8 a[8], b[4];
        #pragma unroll
        for (int mi = 0; mi < 8; ++mi)
            a[mi] = *(const bf16x8*)&Ab[(wr + mi * 16 + lm) * 32 + aslot];
        #pragma unroll
        for (int ni = 0; ni < 4; ++ni)
            b[ni] = *(const bf16x8*)&Bb[(wc + ni * 16 + lm) * 32 + aslot];
        #pragma unroll
        for (int mi = 0; mi < 8; ++mi)
            #pragma unroll
            for (int ni = 0; ni < 4; ++ni)
                acc[mi][ni] = __builtin_amdgcn_mfma_f32_16x16x32_bf16(
                    a[mi], b[ni], acc[mi][ni], 0, 0, 0);

        // counted wait: tile t+1 landed; newest tiles stay in flight
        if (t + 1 < NT) {
            if (t + 3 < NT)      asm volatile("s_waitcnt vmcnt(8)" ::: "memory");
            else if (t + 2 < NT) asm volatile("s_waitcnt vmcnt(4)" ::: "memory");
            else                 asm volatile("s_waitcnt vmcnt(0)" ::: "memory");
            __builtin_amdgcn_s_barrier();
        }
    }
#undef STAGE
#undef ASL
#undef BSL

    // epilogue.  C/D: row=(lane>>4)*4+r, col=lane&15 (m89-verified)
    float lbv = 0.f;
    if constexpr (MODE == 5) lbv = (float)(*lbp);

    if constexpr (MODE == 5 || MODE == 6) {
        const int cbase = (n0 + wc) >> 1;
        #pragma unroll
        for (int nip = 0; nip < 4; nip += 2) {
            const int c = cbase + (nip >> 1) * 16 + lm;
            const float b0 = bias0[c];
            const float b1v = bias1[c];
            #pragma unroll
            for (int mi = 0; mi < 8; ++mi) {
                #pragma unroll
                for (int r = 0; r < 4; ++r) {
                    const size_t row = m0 + wr + mi * 16 + quad * 4 + r;
                    const size_t oidx = row * NOUT + c;
                    float p0 = acc[mi][nip][r]     + b0;
                    float p1 = acc[mi][nip + 1][r] + b1v;
                    if constexpr (MODE == 5) {
                        float si = p0 * sigm(p0);
                        float fv = sigm(p1);
                        float lamv = lbv + (1.f - lbv) * fv;
                        out0[oidx] = f2bf(lamv);
                        out1[oidx] = f2bf((1.f - lamv) * si);
                    } else {
                        out0[oidx] = f2bf(p0 * sigm(p0) * p1);
                    }
                }
            }
        }
    } else {
        #pragma unroll
        for (int ni = 0; ni < 4; ++ni) {
            const int col = n0 + wc + ni * 16 + lm;
            const float bcol = bias0[col];
            #pragma unroll
            for (int mi = 0; mi < 8; ++mi) {
                #pragma unroll
                for (int r = 0; r < 4; ++r) {
                    const size_t row = m0 + wr + mi * 16 + quad * 4 + r;
                    const size_t oidx = row * NOUT + col;
                    float v = acc[mi][ni][r] + bcol;
                    if constexpr (MODE == 0) out0[oidx] = f2bf(v);
                    else                     out0[oidx] = f2bf(sigm(v));
                }
            }
        }
    }
}

// ---------------------------------------------------------------------------
// Scan pass 1: per (b,chunk,d) aggregates in one ascending pass.
// ---------------------------------------------------------------------------
__global__ __launch_bounds__(512)
void scan_agg(const unsigned short* __restrict__ lam, const unsigned short* __restrict__ u,
              float* __restrict__ Aarr, float* __restrict__ Vf, float* __restrict__ Vr)
{
    int bc = blockIdx.x;             // b*CC + c
    int b = bc >> 5, c = bc & 31;
    int d = threadIdx.x;
    size_t base = ((size_t)b * NN + c * LLEN) * DD + d;
    float A = 1.f, vf = 0.f, vr = 0.f;
    for (int t = 0; t < LLEN; ++t) {
        float lv = bf2f(lam[base + (size_t)t * DD]);
        float uv = bf2f(u[base + (size_t)t * DD]);
        vf = lv * vf + uv;
        vr += uv * A;
        A *= lv;
    }
    size_t o = (size_t)bc * DD + d;
    Aarr[o] = A; Vf[o] = vf; Vr[o] = vr;
}

__global__ __launch_bounds__(256)
void scan_comb(const float* __restrict__ Aarr, const float* __restrict__ Vf,
               const float* __restrict__ Vr, float* __restrict__ cf, float* __restrict__ cr)
{
    int g = blockIdx.x * 256 + threadIdx.x;
    int b = g >> 9, d = g & 511;
    float S = 0.f;
    for (int c = 0; c < CC; ++c) {
        size_t o = (size_t)(b * CC + c) * DD + d;
        cf[o] = S;
        S = Vf[o] + Aarr[o] * S;
    }
    S = 0.f;
    for (int c = CC - 1; c >= 0; --c) {
        size_t o = (size_t)(b * CC + c) * DD + d;
        cr[o] = S;
        S = Vr[o] + Aarr[o] * S;
    }
}

__global__ __launch_bounds__(256)
void scan_final(const unsigned short* __restrict__ lam, const unsigned short* __restrict__ u,
                const float* __restrict__ cf, const float* __restrict__ cr,
                float* __restrict__ h)
{
    int bid = blockIdx.x;            // b*64 + c*2 + dhalf
    int dh = bid & 1, c = (bid >> 1) & 31, b = bid >> 6;
    int d = dh * 256 + threadIdx.x;
    size_t base = ((size_t)b * NN + c * LLEN) * DD + d;
    size_t co   = (size_t)(b * CC + c) * DD + d;

    float hbuf[LLEN];
    float hf = cf[co];
    #pragma unroll
    for (int t = 0; t < LLEN; ++t) {
        float lv = bf2f(lam[base + (size_t)t * DD]);
        float uv = bf2f(u[base + (size_t)t * DD]);
        hf = lv * hf + uv;
        hbuf[t] = hf;
    }
    float hr = cr[co];
    #pragma unroll
    for (int t = LLEN - 1; t >= 0; --t) {
        float lv = bf2f(lam[base + (size_t)t * DD]);
        float uv = bf2f(u[base + (size_t)t * DD]);
        hr = lv * hr + uv;
        h[base + (size_t)t * DD] = hbuf[t] + hr;
    }
}

// hg = h * rsqrt(mean(h^2)+1e-6) * g   (bf16 out; in-place over g safe)
__global__ __launch_bounds__(256)
void rms_mul(const float* __restrict__ h, const unsigned short* __restrict__ g,
             unsigned short* __restrict__ hg)
{
    int row = blockIdx.x;
    size_t base = (size_t)row * DD;
    int tid = threadIdx.x, col = tid * 2;
    float2 v = *(const float2*)&h[base + col];
    float ss = v.x * v.x + v.y * v.y;
    #pragma unroll
    for (int off = 32; off > 0; off >>= 1) ss += __shfl_down(ss, off);
    __shared__ float ps[4];
    __shared__ float scale_s;
    if ((tid & 63) == 0) ps[tid >> 6] = ss;
    __syncthreads();
    if (tid == 0) scale_s = rsqrtf((ps[0] + ps[1] + ps[2] + ps[3]) * (1.f / DD) + 1e-6f);
    __syncthreads();
    float sc = scale_s;
    ushort2 gv = *(const ushort2*)&g[base + col];
    ushort2 o;
    o.x = f2bf(v.x * sc * bf2f(gv.x));
    o.y = f2bf(v.y * sc * bf2f(gv.y));
    *(ushort2*)&hg[base + col] = o;
}

// out = xin + layernorm(y)*gam + bet ; optional bf16 copy of out -> outb
__global__ __launch_bounds__(256)
void add_ln(const float* __restrict__ xin, const unsigned short* __restrict__ y,
            const float* __restrict__ gam, const float* __restrict__ bet,
            float* __restrict__ out, unsigned short* __restrict__ outb)
{
    int row = blockIdx.x;
    size_t base = (size_t)row * DD;
    int tid = threadIdx.x, col = tid * 2;
    ushort2 yv = *(const ushort2*)&y[base + col];
    float vx = bf2f(yv.x), vy = bf2f(yv.y);
    float s = vx + vy;
    float ss = vx * vx + vy * vy;
    #pragma unroll
    for (int off = 32; off > 0; off >>= 1) {
        s  += __shfl_down(s, off);
        ss += __shfl_down(ss, off);
    }
    __shared__ float ps[8];
    __shared__ float stats[2];
    if ((tid & 63) == 0) { ps[tid >> 6] = s; ps[4 + (tid >> 6)] = ss; }
    __syncthreads();
    if (tid == 0) {
        float st  = ps[0] + ps[1] + ps[2] + ps[3];
        float sst = ps[4] + ps[5] + ps[6] + ps[7];
        float mean = st * (1.f / DD);
        float var  = sst * (1.f / DD) - mean * mean;
        stats[0] = mean; stats[1] = rsqrtf(var + 1e-5f);
    }
    __syncthreads();
    float mean = stats[0], inv = stats[1];
    float2 xv = *(const float2*)&xin[base + col];
    float2 gv = *(const float2*)&gam[col];
    float2 bv = *(const float2*)&bet[col];
    float2 o;
    o.x = xv.x + (vx - mean) * inv * gv.x + bv.x;
    o.y = xv.y + (vy - mean) * inv * gv.y + bv.y;
    *(float2*)&out[base + col] = o;
    if (outb) {
        ushort2 ob; ob.x = f2bf(o.x); ob.y = f2bf(o.y);
        *(ushort2*)&outb[base + col] = ob;
    }
}

extern "C" void kernel_launch(void* const* d_in, const int* in_sizes, int n_in,
                              void* d_out, int out_size, void* d_ws, size_t ws_size,
                              hipStream_t stream)
{
    const float* x   = (const float*)d_in[0];
    const int*   lb  = (const int*)d_in[1];
    const float* Wi  = (const float*)d_in[2];
    const float* bi  = (const float*)d_in[3];
    const float* Wf  = (const float*)d_in[4];
    const float* bfp = (const float*)d_in[5];
    const float* Wg  = (const float*)d_in[6];
    const float* bg  = (const float*)d_in[7];
    const float* Wo  = (const float*)d_in[8];
    const float* bo  = (const float*)d_in[9];
    const float* tng = (const float*)d_in[10];
    const float* tnb = (const float*)d_in[11];
    const float* fng = (const float*)d_in[12];
    const float* fnb = (const float*)d_in[13];
    const float* W1  = (const float*)d_in[14];
    const float* b1  = (const float*)d_in[15];
    const float* W2  = (const float*)d_in[16];
    const float* b2  = (const float*)d_in[17];
    const float* W3  = (const float*)d_in[18];
    const float* b3  = (const float*)d_in[19];

    // ---- ws layout: [bf16 weights | 4 bf16 slabs | fp32 aggregates] ----
    unsigned short* wbase = (unsigned short*)d_ws;
    unsigned short* WifT = wbase;                  // 1024x512 (Wi|Wf interleaved)
    unsigned short* WgT  = WifT + 524288;          // 512x512
    unsigned short* WoT  = WgT + 262144;           // 512x512
    unsigned short* W12T = WoT + 262144;           // 2048x512 (W1|W2 interleaved)
    unsigned short* W3T  = W12T + 1048576;         // 512x1024
    const size_t WTOT = 524288 + 262144 + 262144 + 1048576 + 524288; // 2,621,440

    wt_prep_pair<<<dim3(32, 16), 256, 0, stream>>>(Wi, Wf, WifT, 512, 512);
    wt_prep<<<dim3(16, 16), 256, 0, stream>>>(Wg, WgT, 512, 512);
    wt_prep<<<dim3(16, 16), 256, 0, stream>>>(Wo, WoT, 512, 512);
    wt_prep_pair<<<dim3(64, 16), 256, 0, stream>>>(W1, W2, W12T, 512, 1024);
    wt_prep<<<dim3(16, 32), 256, 0, stream>>>(W3, W3T, 1024, 512);

    // per batch row: 4 bf16 slabs (NN*DD) + 5 fp32 aggregates (CC*DD)
    const size_t perB = (size_t)4 * NN * DD * 2 + (size_t)5 * CC * DD * 4;
    int Bch = 32;
    while (Bch > 1 && WTOT * 2 + (size_t)Bch * perB > ws_size) Bch >>= 1;
    const int nch = BB / Bch;

    const size_t slabE = (size_t)Bch * NN * DD;   // elements per bf16 slab

    for (int ch = 0; ch < nch; ++ch) {
        const size_t r0 = (size_t)ch * Bch * NN;  // first row of this chunk
        const int Mc = Bch * NN;
        const int Mt = Mc / 256;                  // 256-row m-tiles
        const float* xc = x + r0 * DD;
        unsigned short* S0 = wbase + WTOT;
        unsigned short* S1 = S0 + slabE;
        unsigned short* S2 = S0 + 2 * slabE;
        unsigned short* S3 = S0 + 3 * slabE;
        float* small = (float*)(S0 + 4 * slabE);
        const size_t agg = (size_t)Bch * CC * DD;
        float* Aarr = small;
        float* VfP  = small + agg;
        float* VrP  = small + 2 * agg;
        float* cfP  = small + 3 * agg;
        float* crP  = small + 4 * agg;
        float* hout = (float*)d_out + r0 * DD;    // h -> xr -> final out

        // 0) x -> bf16 (S3)
        cast_bf16<<<Mc / 2, 256, 0, stream>>>(xc, S3);
        // 1) fused i,f GEMM: lam -> S1, u = (1-lam)*silu(i) -> S0
        gemm256<5, 512, 1024><<<Mt * 4, 512, 0, stream>>>(
            S3, WifT, bi, bfp, S1, S0, lb, Mt);
        // 2) g = sigm(x@Wg+bg) -> S2
        gemm256<2, 512, 512><<<Mt * 2, 512, 0, stream>>>(
            S3, WgT, bg, nullptr, S2, nullptr, nullptr, Mt);
        // 3-5) bidirectional chunked scan: lam(S1), u(S0) -> h (fp32, d_out region)
        scan_agg<<<Bch * CC, 512, 0, stream>>>(S1, S0, Aarr, VfP, VrP);
        scan_comb<<<(Bch * DD) / 256, 256, 0, stream>>>(Aarr, VfP, VrP, cfP, crP);
        scan_final<<<Bch * CC * 2, 256, 0, stream>>>(S1, S0, cfP, crP, hout);
        // 6) hg = rms_norm(h)*g -> S2 (in place)
        rms_mul<<<Mc, 256, 0, stream>>>(hout, S2, S2);
        // 7) y2 = hg@Wo + bo -> S0
        gemm256<0, 512, 512><<<Mt * 2, 512, 0, stream>>>(
            S2, WoT, bo, nullptr, S0, nullptr, nullptr, Mt);
        // 8) xr = x + LN(y2)*tn_g+tn_b -> hout (fp32) + S3 (bf16)
        add_ln<<<Mc, 256, 0, stream>>>(xc, S0, tng, tnb, hout, S3);
        // 9) fused W1,W2 GEMM: v = silu(xr@W1+b1)*(xr@W2+b2) -> S1 (spans S1+S2)
        gemm256<6, 512, 2048><<<Mt * 8, 512, 0, stream>>>(
            S3, W12T, b1, b2, S1, nullptr, nullptr, Mt);
        // 10) y4 = v@W3 + b3 -> S0
        gemm256<0, 1024, 512><<<Mt * 2, 512, 0, stream>>>(
            S1, W3T, b3, nullptr, S0, nullptr, nullptr, Mt);
        // 11) out = xr + LN(y4)*fn_g+fn_b (fp32, in place in d_out region)
        add_ln<<<Mc, 256, 0, stream>>>(hout, S0, fng, fnb, hout, nullptr);
    }
}

// Round 3
// 1115.253 us; speedup vs baseline: 1.1350x; 1.1350x over previous
//
#include <hip/hip_runtime.h>
#include <hip/hip_bf16.h>

#define BB 32
#define NN 2048
#define DD 512
#define DGG 1024
#define CC 32          // scan chunks per sequence
#define LLEN 64        // scan chunk length (CC*LLEN == NN)

typedef short bf16x8 __attribute__((ext_vector_type(8)));
typedef float f32x4  __attribute__((ext_vector_type(4)));

__device__ __forceinline__ unsigned short f2bf(float f){
    __hip_bfloat16 h = __float2bfloat16(f);
    return *reinterpret_cast<unsigned short*>(&h);
}
__device__ __forceinline__ float bf2f(unsigned short u){
    unsigned int x = ((unsigned int)u) << 16;
    return __uint_as_float(x);
}
__device__ __forceinline__ float sigm(float x){ return 1.0f/(1.0f + __expf(-x)); }

// async global->LDS, 16B per lane; LDS dest = wave-uniform base + lane*16 (m97/m104)
__device__ __forceinline__ void gl_lds16(const unsigned short* g, unsigned short* l){
    __builtin_amdgcn_global_load_lds(
        (const __attribute__((address_space(1))) unsigned int*)g,
        (__attribute__((address_space(3))) unsigned int*)l, 16, 0, 0);
}

// ---------------------------------------------------------------------------
// Weight prep: transpose + cast  in[K][N] fp32  ->  out[N][K] bf16.
// ---------------------------------------------------------------------------
__global__ __launch_bounds__(256)
void wt_prep(const float* __restrict__ in, unsigned short* __restrict__ out,
             int K, int N)
{
    __shared__ float t[32][33];
    const int tid = threadIdx.x;
    const int r = tid >> 3;            // 0..31
    const int c = (tid & 7) << 2;      // 0,4,..,28
    const int n0 = blockIdx.x * 32;
    const int k0 = blockIdx.y * 32;
    float4 v = *(const float4*)(in + (size_t)(k0 + r) * N + n0 + c);
    t[r][c] = v.x; t[r][c+1] = v.y; t[r][c+2] = v.z; t[r][c+3] = v.w;
    __syncthreads();
    ushort4 o;
    o.x = f2bf(t[c+0][r]); o.y = f2bf(t[c+1][r]);
    o.z = f2bf(t[c+2][r]); o.w = f2bf(t[c+3][r]);
    *(ushort4*)(out + (size_t)(n0 + r) * K + k0 + c) = o;
}

// ---------------------------------------------------------------------------
// Paired weight prep with 16-column interleave (see epilogue pairing).
// ---------------------------------------------------------------------------
__global__ __launch_bounds__(256)
void wt_prep_pair(const float* __restrict__ in0, const float* __restrict__ in1,
                  unsigned short* __restrict__ out, int K, int N)
{
    __shared__ float t[32][33];
    const int tid = threadIdx.x;
    const int bx  = blockIdx.x;            // group of 32 output rows
    const int k0  = blockIdx.y * 32;
    const int kk  = tid >> 3;              // 0..31
    const int rq  = (tid & 7) << 2;        // 0,4,..,28 (stays within one 16-half)
    const float* src = ((rq >> 4) & 1) ? in1 : in0;
    const int c0 = bx * 16 + (rq & 15);
    float4 v = *(const float4*)(src + (size_t)(k0 + kk) * N + c0);
    t[kk][rq] = v.x; t[kk][rq+1] = v.y; t[kk][rq+2] = v.z; t[kk][rq+3] = v.w;
    __syncthreads();
    const int rr = tid >> 3;               // output row within group
    const int kc = (tid & 7) << 2;
    ushort4 o;
    o.x = f2bf(t[kc+0][rr]); o.y = f2bf(t[kc+1][rr]);
    o.z = f2bf(t[kc+2][rr]); o.w = f2bf(t[kc+3][rr]);
    *(ushort4*)(out + (size_t)(bx * 32 + rr) * K + k0 + kc) = o;
}

// fp32 -> bf16 cast, 4 elems/thread
__global__ __launch_bounds__(256)
void cast_bf16(const float* __restrict__ in, unsigned short* __restrict__ out)
{
    size_t i = ((size_t)blockIdx.x * 256 + threadIdx.x) * 4;
    float4 v = *(const float4*)(in + i);
    ushort4 o;
    o.x = f2bf(v.x); o.y = f2bf(v.y); o.z = f2bf(v.z); o.w = f2bf(v.w);
    *(ushort4*)(out + i) = o;
}

// ---------------------------------------------------------------------------
// gemm8p: m201-style 8-phase 256x256 tile, BK=64, double-buffered LDS
// (128 KiB), 8 waves (2Mx4N), wave tile 128x64, acc[8][4] 16x16x32 MFMA.
// Per iteration: 2 K-tiles, 8 phases; each phase = {ds_read quadrant frags,
// stage 1 half-tile (2 x global_load_lds), barrier, lgkmcnt(0),
// setprio(1) + 16 MFMA + setprio(0), barrier}.  Counted vmcnt(4) at the end
// of phases 3 and 7 only (vmcnt(0) only at the last tile).
// LDS slot swizzle: physical 16B-slot = logical ^ (row&7); inverse applied
// on the per-lane global source (rule #21), zero bank conflicts measured.
//   MODE 0: out0 = A@B + bias0
//   MODE 2: out0 = sigmoid(A@B + bias0)
//   MODE 5: paired B (Wi|Wf): si=silu(p0+b0); fv=sigm(p1+b1);
//           lam=lb+(1-lb)*fv -> out0 ; u=(1-lam)*si -> out1   (NOUT=NI/2)
//   MODE 6: paired B (W1|W2): out0 = silu(p0+b0)*(p1+b1)      (NOUT=NI/2)
// ---------------------------------------------------------------------------
template<int MODE, int K, int NI>
__global__ __launch_bounds__(512, 2)
void gemm8p(const unsigned short* __restrict__ A,
            const unsigned short* __restrict__ Bt,
            const float* __restrict__ bias0,
            const float* __restrict__ bias1,
            unsigned short* __restrict__ out0,
            unsigned short* __restrict__ out1,
            const int* __restrict__ lbp, int Mtiles)
{
    constexpr int NKT   = K / 64;                       // K-tiles (>= 8)
    constexpr int ITERS = NKT / 2;
    constexpr int Ntl   = NI / 256;
    constexpr int NOUT  = (MODE >= 5) ? NI / 2 : NI;
    // double buffer: even K-tiles -> *0, odd -> *1.  4 x 32 KiB = 128 KiB.
    __shared__ unsigned short As0[256*64], As1[256*64];
    __shared__ unsigned short Bs0[256*64], Bs1[256*64];

    const int tid  = threadIdx.x;
    const int wave = tid >> 6;
    const int lane = tid & 63;
    const int lm   = lane & 15;
    const int quad = lane >> 4;
    const int wr   = (wave >> 2) * 128;
    const int wc   = (wave & 3) * 64;

    // XCD-aware bijective swizzle (nwg % 8 == 0 for all shapes here), n-fast.
    const int nwg = Mtiles * Ntl;
    const int hb  = blockIdx.x;
    const int wg  = (hb & 7) * (nwg >> 3) + (hb >> 3);
    const int bm  = wg / Ntl;
    const int bn  = wg - bm * Ntl;
    const size_t m0 = (size_t)bm * 256;
    const int    n0 = bn * 256;

    // staging source: thread t covers row (wave*8 + t>>3) of a 64-row chunk,
    // physical slot t&7; global fetches logical slot (t&7)^(row&7).
    const int r8 = lane >> 3;
    const int sl = (lane & 7) ^ r8;
    const unsigned short* gA = A  + (m0 + wave * 8 + r8) * (size_t)K + sl * 8;
    const unsigned short* gB = Bt + ((size_t)n0 + wave * 8 + r8) * K + sl * 8;
    const int ldw = wave * 8 * 64;                      // wave-uniform LDS elems
    const int sx  = lm & 7;                             // read-side row XOR

    // stage one half-tile (128 rows) = 2 gl_lds (2 vm instrs/wave)
#define STG(XS, gX, kt, hh) do {                                              \
        gl_lds16(gX + (size_t)((hh)*128)      * K + (kt)*64,                  \
                 XS + ((hh)*128)      * 64 + ldw);                            \
        gl_lds16(gX + (size_t)((hh)*128 + 64) * K + (kt)*64,                  \
                 XS + ((hh)*128 + 64) * 64 + ldw);                            \
    } while (0)

    // quadrant MFMA: mh selects mi 0..3 / 4..7, nh selects ni pair
#define MFQ(mh, nh, bsel) do {                                                \
        _Pragma("unroll") for (int ks = 0; ks < 2; ++ks)                      \
        _Pragma("unroll") for (int mi = 0; mi < 4; ++mi)                      \
        _Pragma("unroll") for (int ni = 0; ni < 2; ++ni)                      \
            acc[(mh)*4+mi][(nh)*2+ni] = __builtin_amdgcn_mfma_f32_16x16x32_bf16( \
                a[mi][ks], bsel[ni][ks], acc[(mh)*4+mi][(nh)*2+ni], 0, 0, 0); \
    } while (0)

#define RD_A(XS, mh) do {                                                     \
        _Pragma("unroll") for (int ks = 0; ks < 2; ++ks)                      \
        _Pragma("unroll") for (int mi = 0; mi < 4; ++mi)                      \
            a[mi][ks] = *(const bf16x8*)&XS[(wr + ((mh)*4+mi)*16 + lm)*64     \
                                            + ((ks*4+quad) ^ sx)*8];          \
    } while (0)
#define RD_B(XS, nh, breg) do {                                               \
        _Pragma("unroll") for (int ks = 0; ks < 2; ++ks)                      \
        _Pragma("unroll") for (int ni = 0; ni < 2; ++ni)                      \
            breg[ni][ks] = *(const bf16x8*)&XS[(wc + ((nh)*2+ni)*16 + lm)*64  \
                                               + ((ks*4+quad) ^ sx)*8];       \
    } while (0)

#define BARRIER()  __builtin_amdgcn_s_barrier()
#define LGKM0()    asm volatile("s_waitcnt lgkmcnt(0)" ::: "memory")
#define VMC(n)     asm volatile("s_waitcnt vmcnt(" #n ")" ::: "memory")

    f32x4 acc[8][4];
    #pragma unroll
    for (int i = 0; i < 8; ++i)
        #pragma unroll
        for (int j = 0; j < 4; ++j) acc[i][j] = (f32x4){0.f, 0.f, 0.f, 0.f};

    bf16x8 a[4][2], bA[2][2], bB[2][2];

    // prologue: tile 0 complete + tile 1 halves {B.h0, A.h0}; leave 2 halves
    // (4 loads) in flight.
    STG(Bs0, gB, 0, 0); STG(As0, gA, 0, 0); STG(As0, gA, 0, 1);
    STG(Bs0, gB, 0, 1); STG(Bs1, gB, 1, 0); STG(As1, gA, 1, 0);
    VMC(4);
    BARRIER();

    #pragma unroll
    for (int j = 0; j < ITERS; ++j) {
        const bool LAST = (j == ITERS - 1);
        // ---- phase 0: tile 2j, quadrant (mh0,nh0); stage A[2j+1].h1
        RD_A(As0, 0); RD_B(Bs0, 0, bA);
        STG(As1, gA, 2*j + 1, 1);
        BARRIER(); LGKM0();
        __builtin_amdgcn_s_setprio(1); MFQ(0, 0, bA); __builtin_amdgcn_s_setprio(0);
        BARRIER();
        // ---- phase 1: (mh0,nh1); stage B[2j+1].h1
        RD_B(Bs0, 1, bB);
        STG(Bs1, gB, 2*j + 1, 1);
        BARRIER(); LGKM0();
        __builtin_amdgcn_s_setprio(1); MFQ(0, 1, bB); __builtin_amdgcn_s_setprio(0);
        BARRIER();
        // ---- phase 2: (mh1,nh0); stage B[2j+2].h0
        RD_A(As0, 1);
        if (2*j + 2 < NKT) STG(Bs0, gB, 2*j + 2, 0);
        BARRIER(); LGKM0();
        __builtin_amdgcn_s_setprio(1); MFQ(1, 0, bA); __builtin_amdgcn_s_setprio(0);
        BARRIER();
        // ---- phase 3: (mh1,nh1); stage A[2j+2].h0; counted vmcnt
        if (2*j + 2 < NKT) STG(As0, gA, 2*j + 2, 0);
        BARRIER(); LGKM0();
        __builtin_amdgcn_s_setprio(1); MFQ(1, 1, bB); __builtin_amdgcn_s_setprio(0);
        if (LAST) { VMC(0); } else { VMC(4); }
        BARRIER();
        // ---- phase 4: tile 2j+1, (mh0,nh0); stage A[2j+2].h1
        RD_A(As1, 0); RD_B(Bs1, 0, bA);
        if (2*j + 2 < NKT) STG(As0, gA, 2*j + 2, 1);
        BARRIER(); LGKM0();
        __builtin_amdgcn_s_setprio(1); MFQ(0, 0, bA); __builtin_amdgcn_s_setprio(0);
        BARRIER();
        // ---- phase 5: (mh0,nh1); stage B[2j+2].h1
        RD_B(Bs1, 1, bB);
        if (2*j + 2 < NKT) STG(Bs0, gB, 2*j + 2, 1);
        BARRIER(); LGKM0();
        __builtin_amdgcn_s_setprio(1); MFQ(0, 1, bB); __builtin_amdgcn_s_setprio(0);
        BARRIER();
        // ---- phase 6: (mh1,nh0); stage B[2j+3].h0
        RD_A(As1, 1);
        if (2*j + 3 < NKT) STG(Bs1, gB, 2*j + 3, 0);
        BARRIER(); LGKM0();
        __builtin_amdgcn_s_setprio(1); MFQ(1, 0, bA); __builtin_amdgcn_s_setprio(0);
        BARRIER();
        // ---- phase 7: (mh1,nh1); stage A[2j+3].h0; counted vmcnt
        if (2*j + 3 < NKT) STG(As1, gA, 2*j + 3, 0);
        BARRIER(); LGKM0();
        __builtin_amdgcn_s_setprio(1); MFQ(1, 1, bB); __builtin_amdgcn_s_setprio(0);
        if (!LAST) { VMC(4); BARRIER(); }
    }
#undef STG
#undef MFQ
#undef RD_A
#undef RD_B
#undef BARRIER
#undef LGKM0
#undef VMC

    // epilogue.  C/D: row=(lane>>4)*4+r, col=lane&15 (m89-verified)
    float lbv = 0.f;
    if constexpr (MODE == 5) lbv = (float)(*lbp);

    if constexpr (MODE == 5 || MODE == 6) {
        const int cbase = (n0 + wc) >> 1;
        #pragma unroll
        for (int nip = 0; nip < 4; nip += 2) {
            const int c = cbase + (nip >> 1) * 16 + lm;
            const float b0 = bias0[c];
            const float b1v = bias1[c];
            #pragma unroll
            for (int mi = 0; mi < 8; ++mi) {
                #pragma unroll
                for (int r = 0; r < 4; ++r) {
                    const size_t row = m0 + wr + mi * 16 + quad * 4 + r;
                    const size_t oidx = row * NOUT + c;
                    float p0 = acc[mi][nip][r]     + b0;
                    float p1 = acc[mi][nip + 1][r] + b1v;
                    if constexpr (MODE == 5) {
                        float si = p0 * sigm(p0);
                        float fv = sigm(p1);
                        float lamv = lbv + (1.f - lbv) * fv;
                        out0[oidx] = f2bf(lamv);
                        out1[oidx] = f2bf((1.f - lamv) * si);
                    } else {
                        out0[oidx] = f2bf(p0 * sigm(p0) * p1);
                    }
                }
            }
        }
    } else {
        #pragma unroll
        for (int ni = 0; ni < 4; ++ni) {
            const int col = n0 + wc + ni * 16 + lm;
            const float bcol = bias0[col];
            #pragma unroll
            for (int mi = 0; mi < 8; ++mi) {
                #pragma unroll
                for (int r = 0; r < 4; ++r) {
                    const size_t row = m0 + wr + mi * 16 + quad * 4 + r;
                    const size_t oidx = row * NOUT + col;
                    float v = acc[mi][ni][r] + bcol;
                    if constexpr (MODE == 0) out0[oidx] = f2bf(v);
                    else                     out0[oidx] = f2bf(sigm(v));
                }
            }
        }
    }
}

// ---------------------------------------------------------------------------
// Scan pass 1: per (b,chunk,d) aggregates in one ascending pass.
// ---------------------------------------------------------------------------
__global__ __launch_bounds__(512)
void scan_agg(const unsigned short* __restrict__ lam, const unsigned short* __restrict__ u,
              float* __restrict__ Aarr, float* __restrict__ Vf, float* __restrict__ Vr)
{
    int bc = blockIdx.x;             // b*CC + c
    int b = bc >> 5, c = bc & 31;
    int d = threadIdx.x;
    size_t base = ((size_t)b * NN + c * LLEN) * DD + d;
    float A = 1.f, vf = 0.f, vr = 0.f;
    for (int t = 0; t < LLEN; ++t) {
        float lv = bf2f(lam[base + (size_t)t * DD]);
        float uv = bf2f(u[base + (size_t)t * DD]);
        vf = lv * vf + uv;
        vr += uv * A;
        A *= lv;
    }
    size_t o = (size_t)bc * DD + d;
    Aarr[o] = A; Vf[o] = vf; Vr[o] = vr;
}

__global__ __launch_bounds__(256)
void scan_comb(const float* __restrict__ Aarr, const float* __restrict__ Vf,
               const float* __restrict__ Vr, float* __restrict__ cf, float* __restrict__ cr)
{
    int g = blockIdx.x * 256 + threadIdx.x;
    int b = g >> 9, d = g & 511;
    float S = 0.f;
    for (int c = 0; c < CC; ++c) {
        size_t o = (size_t)(b * CC + c) * DD + d;
        cf[o] = S;
        S = Vf[o] + Aarr[o] * S;
    }
    S = 0.f;
    for (int c = CC - 1; c >= 0; --c) {
        size_t o = (size_t)(b * CC + c) * DD + d;
        cr[o] = S;
        S = Vr[o] + Aarr[o] * S;
    }
}

__global__ __launch_bounds__(256)
void scan_final(const unsigned short* __restrict__ lam, const unsigned short* __restrict__ u,
                const float* __restrict__ cf, const float* __restrict__ cr,
                float* __restrict__ h)
{
    int bid = blockIdx.x;            // b*64 + c*2 + dhalf
    int dh = bid & 1, c = (bid >> 1) & 31, b = bid >> 6;
    int d = dh * 256 + threadIdx.x;
    size_t base = ((size_t)b * NN + c * LLEN) * DD + d;
    size_t co   = (size_t)(b * CC + c) * DD + d;

    float hbuf[LLEN];
    float hf = cf[co];
    #pragma unroll
    for (int t = 0; t < LLEN; ++t) {
        float lv = bf2f(lam[base + (size_t)t * DD]);
        float uv = bf2f(u[base + (size_t)t * DD]);
        hf = lv * hf + uv;
        hbuf[t] = hf;
    }
    float hr = cr[co];
    #pragma unroll
    for (int t = LLEN - 1; t >= 0; --t) {
        float lv = bf2f(lam[base + (size_t)t * DD]);
        float uv = bf2f(u[base + (size_t)t * DD]);
        hr = lv * hr + uv;
        h[base + (size_t)t * DD] = hbuf[t] + hr;
    }
}

// hg = h * rsqrt(mean(h^2)+1e-6) * g   (bf16 out; in-place over g safe)
__global__ __launch_bounds__(256)
void rms_mul(const float* __restrict__ h, const unsigned short* __restrict__ g,
             unsigned short* __restrict__ hg)
{
    int row = blockIdx.x;
    size_t base = (size_t)row * DD;
    int tid = threadIdx.x, col = tid * 2;
    float2 v = *(const float2*)&h[base + col];
    float ss = v.x * v.x + v.y * v.y;
    #pragma unroll
    for (int off = 32; off > 0; off >>= 1) ss += __shfl_down(ss, off);
    __shared__ float ps[4];
    __shared__ float scale_s;
    if ((tid & 63) == 0) ps[tid >> 6] = ss;
    __syncthreads();
    if (tid == 0) scale_s = rsqrtf((ps[0] + ps[1] + ps[2] + ps[3]) * (1.f / DD) + 1e-6f);
    __syncthreads();
    float sc = scale_s;
    ushort2 gv = *(const ushort2*)&g[base + col];
    ushort2 o;
    o.x = f2bf(v.x * sc * bf2f(gv.x));
    o.y = f2bf(v.y * sc * bf2f(gv.y));
    *(ushort2*)&hg[base + col] = o;
}

// out = xin + layernorm(y)*gam + bet ; optional bf16 copy of out -> outb
__global__ __launch_bounds__(256)
void add_ln(const float* __restrict__ xin, const unsigned short* __restrict__ y,
            const float* __restrict__ gam, const float* __restrict__ bet,
            float* __restrict__ out, unsigned short* __restrict__ outb)
{
    int row = blockIdx.x;
    size_t base = (size_t)row * DD;
    int tid = threadIdx.x, col = tid * 2;
    ushort2 yv = *(const ushort2*)&y[base + col];
    float vx = bf2f(yv.x), vy = bf2f(yv.y);
    float s = vx + vy;
    float ss = vx * vx + vy * vy;
    #pragma unroll
    for (int off = 32; off > 0; off >>= 1) {
        s  += __shfl_down(s, off);
        ss += __shfl_down(ss, off);
    }
    __shared__ float ps[8];
    __shared__ float stats[2];
    if ((tid & 63) == 0) { ps[tid >> 6] = s; ps[4 + (tid >> 6)] = ss; }
    __syncthreads();
    if (tid == 0) {
        float st  = ps[0] + ps[1] + ps[2] + ps[3];
        float sst = ps[4] + ps[5] + ps[6] + ps[7];
        float mean = st * (1.f / DD);
        float var  = sst * (1.f / DD) - mean * mean;
        stats[0] = mean; stats[1] = rsqrtf(var + 1e-5f);
    }
    __syncthreads();
    float mean = stats[0], inv = stats[1];
    float2 xv = *(const float2*)&xin[base + col];
    float2 gv = *(const float2*)&gam[col];
    float2 bv = *(const float2*)&bet[col];
    float2 o;
    o.x = xv.x + (vx - mean) * inv * gv.x + bv.x;
    o.y = xv.y + (vy - mean) * inv * gv.y + bv.y;
    *(float2*)&out[base + col] = o;
    if (outb) {
        ushort2 ob; ob.x = f2bf(o.x); ob.y = f2bf(o.y);
        *(ushort2*)&outb[base + col] = ob;
    }
}

extern "C" void kernel_launch(void* const* d_in, const int* in_sizes, int n_in,
                              void* d_out, int out_size, void* d_ws, size_t ws_size,
                              hipStream_t stream)
{
    const float* x   = (const float*)d_in[0];
    const int*   lb  = (const int*)d_in[1];
    const float* Wi  = (const float*)d_in[2];
    const float* bi  = (const float*)d_in[3];
    const float* Wf  = (const float*)d_in[4];
    const float* bfp = (const float*)d_in[5];
    const float* Wg  = (const float*)d_in[6];
    const float* bg  = (const float*)d_in[7];
    const float* Wo  = (const float*)d_in[8];
    const float* bo  = (const float*)d_in[9];
    const float* tng = (const float*)d_in[10];
    const float* tnb = (const float*)d_in[11];
    const float* fng = (const float*)d_in[12];
    const float* fnb = (const float*)d_in[13];
    const float* W1  = (const float*)d_in[14];
    const float* b1  = (const float*)d_in[15];
    const float* W2  = (const float*)d_in[16];
    const float* b2  = (const float*)d_in[17];
    const float* W3  = (const float*)d_in[18];
    const float* b3  = (const float*)d_in[19];

    // ---- ws layout: [bf16 weights | 4 bf16 slabs | fp32 aggregates] ----
    unsigned short* wbase = (unsigned short*)d_ws;
    unsigned short* WifT = wbase;                  // 1024x512 (Wi|Wf interleaved)
    unsigned short* WgT  = WifT + 524288;          // 512x512
    unsigned short* WoT  = WgT + 262144;           // 512x512
    unsigned short* W12T = WoT + 262144;           // 2048x512 (W1|W2 interleaved)
    unsigned short* W3T  = W12T + 1048576;         // 512x1024
    const size_t WTOT = 524288 + 262144 + 262144 + 1048576 + 524288; // 2,621,440

    wt_prep_pair<<<dim3(32, 16), 256, 0, stream>>>(Wi, Wf, WifT, 512, 512);
    wt_prep<<<dim3(16, 16), 256, 0, stream>>>(Wg, WgT, 512, 512);
    wt_prep<<<dim3(16, 16), 256, 0, stream>>>(Wo, WoT, 512, 512);
    wt_prep_pair<<<dim3(64, 16), 256, 0, stream>>>(W1, W2, W12T, 512, 1024);
    wt_prep<<<dim3(16, 32), 256, 0, stream>>>(W3, W3T, 1024, 512);

    // per batch row: 4 bf16 slabs (NN*DD) + 5 fp32 aggregates (CC*DD)
    const size_t perB = (size_t)4 * NN * DD * 2 + (size_t)5 * CC * DD * 4;
    int Bch = 32;
    while (Bch > 1 && WTOT * 2 + (size_t)Bch * perB > ws_size) Bch >>= 1;
    const int nch = BB / Bch;

    const size_t slabE = (size_t)Bch * NN * DD;   // elements per bf16 slab

    for (int ch = 0; ch < nch; ++ch) {
        const size_t r0 = (size_t)ch * Bch * NN;  // first row of this chunk
        const int Mc = Bch * NN;
        const int Mt = Mc / 256;                  // 256-row m-tiles
        const float* xc = x + r0 * DD;
        unsigned short* S0 = wbase + WTOT;
        unsigned short* S1 = S0 + slabE;
        unsigned short* S2 = S0 + 2 * slabE;
        unsigned short* S3 = S0 + 3 * slabE;
        float* small = (float*)(S0 + 4 * slabE);
        const size_t agg = (size_t)Bch * CC * DD;
        float* Aarr = small;
        float* VfP  = small + agg;
        float* VrP  = small + 2 * agg;
        float* cfP  = small + 3 * agg;
        float* crP  = small + 4 * agg;
        float* hout = (float*)d_out + r0 * DD;    // h -> xr -> final out

        // 0) x -> bf16 (S3)
        cast_bf16<<<Mc / 2, 256, 0, stream>>>(xc, S3);
        // 1) fused i,f GEMM: lam -> S1, u = (1-lam)*silu(i) -> S0
        gemm8p<5, 512, 1024><<<Mt * 4, 512, 0, stream>>>(
            S3, WifT, bi, bfp, S1, S0, lb, Mt);
        // 2) g = sigm(x@Wg+bg) -> S2
        gemm8p<2, 512, 512><<<Mt * 2, 512, 0, stream>>>(
            S3, WgT, bg, nullptr, S2, nullptr, nullptr, Mt);
        // 3-5) bidirectional chunked scan: lam(S1), u(S0) -> h (fp32, d_out region)
        scan_agg<<<Bch * CC, 512, 0, stream>>>(S1, S0, Aarr, VfP, VrP);
        scan_comb<<<(Bch * DD) / 256, 256, 0, stream>>>(Aarr, VfP, VrP, cfP, crP);
        scan_final<<<Bch * CC * 2, 256, 0, stream>>>(S1, S0, cfP, crP, hout);
        // 6) hg = rms_norm(h)*g -> S2 (in place)
        rms_mul<<<Mc, 256, 0, stream>>>(hout, S2, S2);
        // 7) y2 = hg@Wo + bo -> S0
        gemm8p<0, 512, 512><<<Mt * 2, 512, 0, stream>>>(
            S2, WoT, bo, nullptr, S0, nullptr, nullptr, Mt);
        // 8) xr = x + LN(y2)*tn_g+tn_b -> hout (fp32) + S3 (bf16)
        add_ln<<<Mc, 256, 0, stream>>>(xc, S0, tng, tnb, hout, S3);
        // 9) fused W1,W2 GEMM: v = silu(xr@W1+b1)*(xr@W2+b2) -> S1 (spans S1+S2)
        gemm8p<6, 512, 2048><<<Mt * 8, 512, 0, stream>>>(
            S3, W12T, b1, b2, S1, nullptr, nullptr, Mt);
        // 10) y4 = v@W3 + b3 -> S0
        gemm8p<0, 1024, 512><<<Mt * 2, 512, 0, stream>>>(
            S1, W3T, b3, nullptr, S0, nullptr, nullptr, Mt);
        // 11) out = xr + LN(y4)*fn_g+fn_b (fp32, in place in d_out region)
        add_ln<<<Mc, 256, 0, stream>>>(hout, S0, fng, fnb, hout, nullptr);
    }
}